// Round 5
// baseline (684.856 us; speedup 1.0000x reference)
//
#include <hip/hip_runtime.h>

// RecurrentActorCritic B=512,T=512,S=64,H=128,A=8 (fp32 I/O).
// R15: p2 drops the 4 dedicated staging waves (R14: 12 waves, step=2011cyc,
// VALU-issue bound at 1166cyc/SIMD/step; staging waves = +50% barrier
// participants for ~0.4 instr/step of work). Now 512 threads: the 8 MFMA
// waves also stage (3x ushort4/chain/chunk/thread, same chunk-dbuf timing:
// loads for c+1 issued at c start, ds_write at j=15, consumed in c+1 --
// preserves R14's hazard-free ordering of hnew-writes vs gx-reads).
// p1 byte-identical to R11 (MFMA GEMM). p3 byte-identical to R14.

typedef _Float16 h2t __attribute__((ext_vector_type(2)));
typedef _Float16 f16x4 __attribute__((ext_vector_type(4)));
typedef _Float16 f16x8 __attribute__((ext_vector_type(8)));
typedef float f32x4 __attribute__((ext_vector_type(4)));

// LDS-only barrier: drain ds ops, leave global loads/stores in flight.
#define BAR() __asm__ volatile("s_waitcnt lgkmcnt(0)\n\ts_barrier" ::: "memory")

#define BB 512
#define TT 512
#define SS 64
#define HH 128
#define AA 8
#define CK 16
#define NCK (TT / CK)
#define VALO (BB * TT * AA)
#define HFIN (VALO + BB * TT)

// ======================= PHASE 1 (MFMA, unchanged from R11) =======================
__global__ void __launch_bounds__(256, 2) p1_kernel(
    const float* __restrict__ x,   const float* __restrict__ Wf,
    const float* __restrict__ bfe, const float* __restrict__ gf,
    const float* __restrict__ btf, const float* __restrict__ Wih,
    const float* __restrict__ bih, unsigned short* __restrict__ gxws)
{
    const int tid = threadIdx.x;
    const int wv  = tid >> 6;
    const int l   = tid & 63;
    const int lo  = l & 15;
    const int hi  = l >> 4;
    const size_t m0 = (size_t)blockIdx.x * 64;

    __shared__ __align__(16) _Float16 xh[64][72];
    __shared__ __align__(16) float    fb[64][132];
    __shared__ __align__(16) _Float16 zh[64][136];

    {
        const int r  = tid >> 2;
        const int c0 = (tid & 3) << 4;
        const float4* px = (const float4*)(x + (m0 + (size_t)r) * SS + c0);
        float4 a = px[0], b = px[1], c = px[2], d = px[3];
        f16x8 h0, h1;
        h0[0]=(_Float16)a.x; h0[1]=(_Float16)a.y; h0[2]=(_Float16)a.z; h0[3]=(_Float16)a.w;
        h0[4]=(_Float16)b.x; h0[5]=(_Float16)b.y; h0[6]=(_Float16)b.z; h0[7]=(_Float16)b.w;
        h1[0]=(_Float16)c.x; h1[1]=(_Float16)c.y; h1[2]=(_Float16)c.z; h1[3]=(_Float16)c.w;
        h1[4]=(_Float16)d.x; h1[5]=(_Float16)d.y; h1[6]=(_Float16)d.z; h1[7]=(_Float16)d.w;
        *(f16x8*)&xh[r][c0]     = h0;
        *(f16x8*)&xh[r][c0 + 8] = h1;
    }
    __syncthreads();

    {
        const int n0 = wv << 5;
        f32x4 acc[4][2];
        #pragma unroll
        for (int mt = 0; mt < 4; ++mt)
            #pragma unroll
            for (int nt = 0; nt < 2; ++nt) {
                acc[mt][nt][0]=0.f; acc[mt][nt][1]=0.f;
                acc[mt][nt][2]=0.f; acc[mt][nt][3]=0.f;
            }
        #pragma unroll
        for (int kk = 0; kk < 2; ++kk) {
            f16x8 bf[2];
            #pragma unroll
            for (int nt = 0; nt < 2; ++nt) {
                const float4* wp = (const float4*)(Wf + (size_t)(n0 + nt*16 + lo) * SS + kk*32 + hi*8);
                float4 w0 = wp[0], w1 = wp[1];
                f16x8 t;
                t[0]=(_Float16)w0.x; t[1]=(_Float16)w0.y; t[2]=(_Float16)w0.z; t[3]=(_Float16)w0.w;
                t[4]=(_Float16)w1.x; t[5]=(_Float16)w1.y; t[6]=(_Float16)w1.z; t[7]=(_Float16)w1.w;
                bf[nt] = t;
            }
            #pragma unroll
            for (int mt = 0; mt < 4; ++mt) {
                f16x8 af = *(const f16x8*)&xh[mt*16 + lo][kk*32 + hi*8];
                acc[mt][0] = __builtin_amdgcn_mfma_f32_16x16x32_f16(af, bf[0], acc[mt][0], 0, 0, 0);
                acc[mt][1] = __builtin_amdgcn_mfma_f32_16x16x32_f16(af, bf[1], acc[mt][1], 0, 0, 0);
            }
        }
        const float b0 = bfe[n0 + lo];
        const float b1 = bfe[n0 + 16 + lo];
        #pragma unroll
        for (int mt = 0; mt < 4; ++mt)
            #pragma unroll
            for (int j = 0; j < 4; ++j) {
                fb[mt*16 + hi*4 + j][n0 + lo]      = acc[mt][0][j] + b0;
                fb[mt*16 + hi*4 + j][n0 + 16 + lo] = acc[mt][1][j] + b1;
            }
    }
    __syncthreads();

    {
        const int r = tid >> 2;
        const int q = tid & 3;
        const float4* pf = (const float4*)&fb[r][q << 5];
        float4 v[8];
        float s = 0.f, ss = 0.f;
        #pragma unroll
        for (int i = 0; i < 8; ++i) {
            float4 t = pf[i]; v[i] = t;
            s  += (t.x + t.y) + (t.z + t.w);
            ss += (t.x*t.x + t.y*t.y) + (t.z*t.z + t.w*t.w);
        }
        s  += __shfl_xor(s, 1);  s  += __shfl_xor(s, 2);
        ss += __shfl_xor(ss, 1); ss += __shfl_xor(ss, 2);
        const float mu   = s * (1.f / 128.f);
        const float rstd = rsqrtf(ss * (1.f / 128.f) - mu * mu + 1e-5f);
        const float4* pg = (const float4*)(gf  + (q << 5));
        const float4* pb = (const float4*)(btf + (q << 5));
        #pragma unroll
        for (int i = 0; i < 8; ++i) {
            float4 g = pg[i], bb = pb[i], t = v[i];
            h2t pA, pB;
            pA.x = (_Float16)fmaxf((t.x - mu) * rstd * g.x + bb.x, 0.f);
            pA.y = (_Float16)fmaxf((t.y - mu) * rstd * g.y + bb.y, 0.f);
            pB.x = (_Float16)fmaxf((t.z - mu) * rstd * g.z + bb.z, 0.f);
            pB.y = (_Float16)fmaxf((t.w - mu) * rstd * g.w + bb.w, 0.f);
            uint2 u;
            u.x = __builtin_bit_cast(unsigned int, pA);
            u.y = __builtin_bit_cast(unsigned int, pB);
            *(uint2*)&zh[r][(q << 5) + i * 4] = u;
        }
    }
    __syncthreads();

    {
        const int n0 = wv * 96;
        f16x8 bz[4][4];
        #pragma unroll
        for (int mt = 0; mt < 4; ++mt)
            #pragma unroll
            for (int ks = 0; ks < 4; ++ks)
                bz[mt][ks] = *(const f16x8*)&zh[mt*16 + lo][ks*32 + hi*8];
        #pragma unroll
        for (int nt = 0; nt < 6; ++nt) {
            const int nb = n0 + nt * 16;
            const float4 b4 = *(const float4*)(bih + nb + (hi << 2));
            const float* wr = Wih + (size_t)(nb + lo) * HH;
            f32x4 acc[4];
            #pragma unroll
            for (int mt = 0; mt < 4; ++mt) {
                acc[mt][0]=0.f; acc[mt][1]=0.f; acc[mt][2]=0.f; acc[mt][3]=0.f;
            }
            #pragma unroll
            for (int ks = 0; ks < 4; ++ks) {
                const float4* wp = (const float4*)(wr + ks*32 + hi*8);
                float4 w0 = wp[0], w1 = wp[1];
                f16x8 af;
                af[0]=(_Float16)w0.x; af[1]=(_Float16)w0.y; af[2]=(_Float16)w0.z; af[3]=(_Float16)w0.w;
                af[4]=(_Float16)w1.x; af[5]=(_Float16)w1.y; af[6]=(_Float16)w1.z; af[7]=(_Float16)w1.w;
                #pragma unroll
                for (int mt = 0; mt < 4; ++mt)
                    acc[mt] = __builtin_amdgcn_mfma_f32_16x16x32_f16(af, bz[mt][ks], acc[mt], 0, 0, 0);
            }
            #pragma unroll
            for (int mt = 0; mt < 4; ++mt) {
                h2t pA, pB;
                pA.x = (_Float16)(acc[mt][0] + b4.x);
                pA.y = (_Float16)(acc[mt][1] + b4.y);
                pB.x = (_Float16)(acc[mt][2] + b4.z);
                pB.y = (_Float16)(acc[mt][3] + b4.w);
                uint2 u;
                u.x = __builtin_bit_cast(unsigned int, pA);
                u.y = __builtin_bit_cast(unsigned int, pB);
                *(uint2*)(gxws + (m0 + (size_t)(mt*16 + lo)) * 384 + nb + (hi << 2)) = u;
            }
        }
    }
}

// ======================= PHASE 2 (MFMA recurrence, 8 waves total) =======================
// 256 blocks x 512 threads. All 8 waves: mfma matvec + fused gates (chain=lo&1)
// + cooperative gx staging (3 ushort4/chain/chunk/thread).
__global__ void __launch_bounds__(512, 2) p2_kernel(
    const float* __restrict__ hx,  const int* __restrict__ done,
    const float* __restrict__ Whh, const float* __restrict__ bhh,
    unsigned short* __restrict__ gxws, float* __restrict__ out)
{
    const int tid = threadIdx.x;
    const int blk = blockIdx.x;

    __shared__ __align__(16) _Float16 hsh16[2][2][160];      // [buf][chain][pad160]
    __shared__ __align__(16) _Float16 gxb[2][2][CK][384];    // [chain][buf][t][3H] 48 KB
    __shared__ int dsh[2][TT];

    const int lo = tid & 15;
    const int hi = (tid & 63) >> 4;
    const int wv = tid >> 6;          // 0..7
    const int Y  = lo & 1;            // chain owned by this mfma lane
    const int d0 = wv * 16 + hi * 4;

    // ---- persistent state: Whh A-frags + bias + hprev ----
    f16x8 aW[3][4];
    f32x4 bias[3];
    float hp[4];
    {
        #pragma unroll
        for (int q = 0; q < 3; ++q) {
            const float* wr = Whh + (size_t)(q * 128 + wv * 16 + lo) * HH;
            #pragma unroll
            for (int ks = 0; ks < 4; ++ks) {
                const float4* wp = (const float4*)(wr + ks * 32 + hi * 8);
                float4 w0 = wp[0], w1 = wp[1];
                f16x8 t;
                t[0]=(_Float16)w0.x; t[1]=(_Float16)w0.y; t[2]=(_Float16)w0.z; t[3]=(_Float16)w0.w;
                t[4]=(_Float16)w1.x; t[5]=(_Float16)w1.y; t[6]=(_Float16)w1.z; t[7]=(_Float16)w1.w;
                aW[q][ks] = t;
            }
            bias[q] = *(const f32x4*)&bhh[q * 128 + wv * 16 + hi * 4];
        }
        const float4 h4 = *(const float4*)&hx[(size_t)(2 * blk + Y) * HH + d0];
        hp[0]=h4.x; hp[1]=h4.y; hp[2]=h4.z; hp[3]=h4.w;
    }

    if (tid < 256) {
        const int Yc = tid >> 7, d = tid & 127;
        hsh16[0][Yc][d] = (_Float16)hx[(size_t)(2 * blk + Yc) * HH + d];
    }
    for (int idx = tid; idx < 2 * TT; idx += 512)
        dsh[idx >> 9][idx & 511] = done[(2 * blk + (idx >> 9)) * TT + (idx & 511)];

    // ---- cooperative gx staging: 3 ushort4 (8B) per chain per chunk per thread ----
    const unsigned short* baseA = gxws + (size_t)(2 * blk + 0) * TT * 384;
    const unsigned short* baseB = gxws + (size_t)(2 * blk + 1) * TT * 384;
    ushort4 rA0, rA1, rA2, rB0, rB1, rB2;
    {   // chunk 0 -> buffer 0
        const ushort4* ca = (const ushort4*)baseA;
        const ushort4* cb = (const ushort4*)baseB;
        rA0=ca[tid]; rA1=ca[512+tid]; rA2=ca[1024+tid];
        rB0=cb[tid]; rB1=cb[512+tid]; rB2=cb[1024+tid];
        ushort4* ga = (ushort4*)&gxb[0][0][0][0];
        ushort4* gb = (ushort4*)&gxb[1][0][0][0];
        ga[tid]=rA0; ga[512+tid]=rA1; ga[1024+tid]=rA2;
        gb[tid]=rB0; gb[512+tid]=rB1; gb[1024+tid]=rB2;
    }
    __syncthreads();

    for (int c = 0; c < NCK; ++c) {
        if (c + 1 < NCK) {   // issue next-chunk loads (16-step slack)
            const ushort4* ca = (const ushort4*)(baseA + (size_t)(c + 1) * CK * 384);
            const ushort4* cb = (const ushort4*)(baseB + (size_t)(c + 1) * CK * 384);
            rA0=ca[tid]; rA1=ca[512+tid]; rA2=ca[1024+tid];
            rB0=cb[tid]; rB1=cb[512+tid]; rB2=cb[1024+tid];
        }
        for (int j = 0; j < CK; ++j) {
            const int t = c * CK + j;
            {
                const _Float16* hb = hsh16[t & 1][Y];
                f16x8 B0 = *(const f16x8*)&hb[0  + hi*8];
                f16x8 B1 = *(const f16x8*)&hb[32 + hi*8];
                f16x8 B2 = *(const f16x8*)&hb[64 + hi*8];
                f16x8 B3 = *(const f16x8*)&hb[96 + hi*8];
                const _Float16* gxp = gxb[Y][c & 1][j];
                f16x4 g0 = *(const f16x4*)&gxp[d0];
                f16x4 g1 = *(const f16x4*)&gxp[128 + d0];
                f16x4 g2 = *(const f16x4*)&gxp[256 + d0];
                const float mask = dsh[Y][t] ? 0.f : 1.f;
                f32x4 a0 = bias[0], a1 = bias[1], a2 = bias[2];
                a0 = __builtin_amdgcn_mfma_f32_16x16x32_f16(aW[0][0], B0, a0, 0, 0, 0);
                a1 = __builtin_amdgcn_mfma_f32_16x16x32_f16(aW[1][0], B0, a1, 0, 0, 0);
                a2 = __builtin_amdgcn_mfma_f32_16x16x32_f16(aW[2][0], B0, a2, 0, 0, 0);
                a0 = __builtin_amdgcn_mfma_f32_16x16x32_f16(aW[0][1], B1, a0, 0, 0, 0);
                a1 = __builtin_amdgcn_mfma_f32_16x16x32_f16(aW[1][1], B1, a1, 0, 0, 0);
                a2 = __builtin_amdgcn_mfma_f32_16x16x32_f16(aW[2][1], B1, a2, 0, 0, 0);
                a0 = __builtin_amdgcn_mfma_f32_16x16x32_f16(aW[0][2], B2, a0, 0, 0, 0);
                a1 = __builtin_amdgcn_mfma_f32_16x16x32_f16(aW[1][2], B2, a1, 0, 0, 0);
                a2 = __builtin_amdgcn_mfma_f32_16x16x32_f16(aW[2][2], B2, a2, 0, 0, 0);
                a0 = __builtin_amdgcn_mfma_f32_16x16x32_f16(aW[0][3], B3, a0, 0, 0, 0);
                a1 = __builtin_amdgcn_mfma_f32_16x16x32_f16(aW[1][3], B3, a1, 0, 0, 0);
                a2 = __builtin_amdgcn_mfma_f32_16x16x32_f16(aW[2][3], B3, a2, 0, 0, 0);
                // fused gates (rcpf sigmoid/tanh); lane owns d0..d0+3 of chain Y
                float hnA[4], hmA[4];
                #pragma unroll
                for (int jj = 0; jj < 4; ++jj) {
                    float xr = (float)g0[jj] + a0[jj];
                    float xz = (float)g1[jj] + a1[jj];
                    float r_ = __builtin_amdgcn_rcpf(1.f + __expf(-xr));
                    float u_ = __builtin_amdgcn_rcpf(1.f + __expf(-xz));
                    float a_ = (float)g2[jj] + r_ * a2[jj];
                    a_ = fminf(fmaxf(a_, -20.f), 20.f);
                    float e2 = __expf(2.f * a_);
                    float nn = 1.f - 2.f * __builtin_amdgcn_rcpf(e2 + 1.f);
                    float hnew = (1.f - u_) * nn + u_ * hp[jj];
                    float hm = hnew * mask;
                    hp[jj] = hm;
                    hnA[jj] = hnew;
                    hmA[jj] = hm;
                }
                if (lo < 2) {
                    // stream hnew (pre-mask) to ws for p3 (fp32, in gxws slot)
                    float* hw = (float*)(gxws + ((size_t)(2 * blk + Y) * TT + t) * 384);
                    *(float4*)&hw[d0] = make_float4(hnA[0], hnA[1], hnA[2], hnA[3]);
                    h2t p0, p1v;
                    p0.x  = (_Float16)hmA[0]; p0.y  = (_Float16)hmA[1];
                    p1v.x = (_Float16)hmA[2]; p1v.y = (_Float16)hmA[3];
                    uint2 u;
                    u.x = __builtin_bit_cast(unsigned int, p0);
                    u.y = __builtin_bit_cast(unsigned int, p1v);
                    *(uint2*)&hsh16[(t + 1) & 1][Y][d0] = u;
                    if (t == TT - 1) {
                        *(float4*)&out[HFIN + (size_t)(2 * blk + Y) * HH + d0] =
                            make_float4(hmA[0], hmA[1], hmA[2], hmA[3]);
                    }
                }
            }
            if (j == CK - 1 && c + 1 < NCK) {  // write staged regs into opposite buffer
                const int nb = (c + 1) & 1;
                ushort4* ga = (ushort4*)&gxb[0][nb][0][0];
                ushort4* gb = (ushort4*)&gxb[1][nb][0][0];
                ga[tid]=rA0; ga[512+tid]=rA1; ga[1024+tid]=rA2;
                gb[tid]=rB0; gb[512+tid]=rB1; gb[1024+tid]=rB2;
            }
            BAR();
        }
    }
}

// ======================= PHASE 3 (LN + heads, wide — unchanged from R14) =======================
__global__ void __launch_bounds__(256, 2) p3_kernel(
    const unsigned short* __restrict__ gxws,
    const float* __restrict__ gr,  const float* __restrict__ btr,
    const float* __restrict__ Wp,  const float* __restrict__ bp,
    const float* __restrict__ Wv,  const float* __restrict__ bv,
    float* __restrict__ out)
{
    const int tid = threadIdx.x;
    __shared__ __align__(16) float wpl[9][132];
    __shared__ float bpl[9];

    for (int idx = tid; idx < 9 * HH; idx += 256) {
        int row = idx >> 7, col = idx & 127;
        wpl[row][col] = (row < 8) ? Wp[row * HH + col] : Wv[col];
    }
    if (tid < 9) bpl[tid] = (tid < 8) ? bp[tid] : bv[0];

    const size_t m = (size_t)blockIdx.x * 64 + (tid >> 2);
    const int q = tid & 3;
    const float* hr = (const float*)(gxws + m * 384);

    float4 v[8];
    float s = 0.f, ss = 0.f;
    #pragma unroll
    for (int j = 0; j < 8; ++j) {
        float4 t = ((const float4*)hr)[q + 4 * j];
        v[j] = t;
        s  += (t.x + t.y) + (t.z + t.w);
        ss += (t.x*t.x + t.y*t.y) + (t.z*t.z + t.w*t.w);
    }
    s  += __shfl_xor(s, 1);  s  += __shfl_xor(s, 2);
    ss += __shfl_xor(ss, 1); ss += __shfl_xor(ss, 2);
    const float mu   = s * (1.f / 128.f);
    const float rstd = rsqrtf(ss * (1.f / 128.f) - mu * mu + 1e-5f);

    float4 y[8];
    #pragma unroll
    for (int j = 0; j < 8; ++j) {
        float4 g  = ((const float4*)gr)[q + 4 * j];
        float4 bb = ((const float4*)btr)[q + 4 * j];
        float4 t = v[j];
        y[j].x = (t.x - mu) * rstd * g.x + bb.x;
        y[j].y = (t.y - mu) * rstd * g.y + bb.y;
        y[j].z = (t.z - mu) * rstd * g.z + bb.z;
        y[j].w = (t.w - mu) * rstd * g.w + bb.w;
    }
    __syncthreads();   // wpl staged

    float acc[9];
    #pragma unroll
    for (int hd = 0; hd < 9; ++hd) {
        float a = 0.f;
        #pragma unroll
        for (int j = 0; j < 8; ++j) {
            float4 w = ((const float4*)wpl[hd])[q + 4 * j];
            a += (y[j].x * w.x + y[j].y * w.y) + (y[j].z * w.z + y[j].w * w.w);
        }
        acc[hd] = a;
    }
    #pragma unroll
    for (int hd = 0; hd < 9; ++hd) {
        acc[hd] += __shfl_xor(acc[hd], 1);
        acc[hd] += __shfl_xor(acc[hd], 2);
    }
    if (q == 0) {
        float4 o0 = make_float4(acc[0] + bpl[0], acc[1] + bpl[1], acc[2] + bpl[2], acc[3] + bpl[3]);
        float4 o1 = make_float4(acc[4] + bpl[4], acc[5] + bpl[5], acc[6] + bpl[6], acc[7] + bpl[7]);
        ((float4*)(out + m * AA))[0] = o0;
        ((float4*)(out + m * AA))[1] = o1;
    } else if (q == 1) {
        out[VALO + m] = acc[8] + bpl[8];
    }
}

extern "C" void kernel_launch(void* const* d_in, const int* in_sizes, int n_in,
                              void* d_out, int out_size, void* d_ws, size_t ws_size,
                              hipStream_t stream) {
    const float* x   = (const float*)d_in[0];
    const float* hx  = (const float*)d_in[1];
    const int*   dn  = (const int*)d_in[2];
    const float* Wf  = (const float*)d_in[3];
    const float* bfe = (const float*)d_in[4];
    const float* gf  = (const float*)d_in[5];
    const float* btf = (const float*)d_in[6];
    const float* Wih = (const float*)d_in[7];
    const float* Whh = (const float*)d_in[8];
    const float* bih = (const float*)d_in[9];
    const float* bhh = (const float*)d_in[10];
    const float* gr  = (const float*)d_in[11];
    const float* btr = (const float*)d_in[12];
    const float* Wp  = (const float*)d_in[13];
    const float* bp  = (const float*)d_in[14];
    const float* Wv  = (const float*)d_in[15];
    const float* bv  = (const float*)d_in[16];
    float* out = (float*)d_out;

    unsigned short* gxws = (unsigned short*)d_ws;   // 201.3 MB gx buffer (+hraw reuse)
    hipLaunchKernelGGL(p1_kernel, dim3(BB * TT / 64), dim3(256), 0, stream,
                       x, Wf, bfe, gf, btf, Wih, bih, gxws);
    hipLaunchKernelGGL(p2_kernel, dim3(BB / 2), dim3(512), 0, stream,
                       hx, dn, Whh, bhh, gxws, out);
    hipLaunchKernelGGL(p3_kernel, dim3(BB * TT / 64), dim3(256), 0, stream,
                       gxws, gr, btr, Wp, bp, Wv, bv, out);
}

// Round 7
// 636.711 us; speedup vs baseline: 1.0756x; 1.0756x over previous
//
#include <hip/hip_runtime.h>

// RecurrentActorCritic B=512,T=512,S=64,H=128,A=8 (fp32 I/O).
// R17 = R16 with cvt_pkrtz type fix (builtin returns __fp16x2, bit_cast
// to uint directly). p2 source-level VALU diet: R15 post-mortem showed
// step=2025cyc invariant to wave count => per-SIMD VALU issue bound
// (~280 instr/wave/step vs ~120 ideal). Cuts: (1) j-unroll x2 -> static
// buffer parities; (2) gx/hraw pointer increments; (3) mask as float LDS;
// (4) v_cvt_pkrtz pack; (5) exp2-form gates; (6) final store -> epilogue.
// p1 byte-identical to R11. p3 byte-identical to R14.

typedef _Float16 h2t __attribute__((ext_vector_type(2)));
typedef _Float16 f16x4 __attribute__((ext_vector_type(4)));
typedef _Float16 f16x8 __attribute__((ext_vector_type(8)));
typedef float f32x4 __attribute__((ext_vector_type(4)));

// LDS-only barrier: drain ds ops, leave global loads/stores in flight.
#define BAR() __asm__ volatile("s_waitcnt lgkmcnt(0)\n\ts_barrier" ::: "memory")

#define BB 512
#define TT 512
#define SS 64
#define HH 128
#define AA 8
#define CK 16
#define NCK (TT / CK)
#define VALO (BB * TT * AA)
#define HFIN (VALO + BB * TT)

// ======================= PHASE 1 (MFMA, unchanged from R11) =======================
__global__ void __launch_bounds__(256, 2) p1_kernel(
    const float* __restrict__ x,   const float* __restrict__ Wf,
    const float* __restrict__ bfe, const float* __restrict__ gf,
    const float* __restrict__ btf, const float* __restrict__ Wih,
    const float* __restrict__ bih, unsigned short* __restrict__ gxws)
{
    const int tid = threadIdx.x;
    const int wv  = tid >> 6;
    const int l   = tid & 63;
    const int lo  = l & 15;
    const int hi  = l >> 4;
    const size_t m0 = (size_t)blockIdx.x * 64;

    __shared__ __align__(16) _Float16 xh[64][72];
    __shared__ __align__(16) float    fb[64][132];
    __shared__ __align__(16) _Float16 zh[64][136];

    {
        const int r  = tid >> 2;
        const int c0 = (tid & 3) << 4;
        const float4* px = (const float4*)(x + (m0 + (size_t)r) * SS + c0);
        float4 a = px[0], b = px[1], c = px[2], d = px[3];
        f16x8 h0, h1;
        h0[0]=(_Float16)a.x; h0[1]=(_Float16)a.y; h0[2]=(_Float16)a.z; h0[3]=(_Float16)a.w;
        h0[4]=(_Float16)b.x; h0[5]=(_Float16)b.y; h0[6]=(_Float16)b.z; h0[7]=(_Float16)b.w;
        h1[0]=(_Float16)c.x; h1[1]=(_Float16)c.y; h1[2]=(_Float16)c.z; h1[3]=(_Float16)c.w;
        h1[4]=(_Float16)d.x; h1[5]=(_Float16)d.y; h1[6]=(_Float16)d.z; h1[7]=(_Float16)d.w;
        *(f16x8*)&xh[r][c0]     = h0;
        *(f16x8*)&xh[r][c0 + 8] = h1;
    }
    __syncthreads();

    {
        const int n0 = wv << 5;
        f32x4 acc[4][2];
        #pragma unroll
        for (int mt = 0; mt < 4; ++mt)
            #pragma unroll
            for (int nt = 0; nt < 2; ++nt) {
                acc[mt][nt][0]=0.f; acc[mt][nt][1]=0.f;
                acc[mt][nt][2]=0.f; acc[mt][nt][3]=0.f;
            }
        #pragma unroll
        for (int kk = 0; kk < 2; ++kk) {
            f16x8 bf[2];
            #pragma unroll
            for (int nt = 0; nt < 2; ++nt) {
                const float4* wp = (const float4*)(Wf + (size_t)(n0 + nt*16 + lo) * SS + kk*32 + hi*8);
                float4 w0 = wp[0], w1 = wp[1];
                f16x8 t;
                t[0]=(_Float16)w0.x; t[1]=(_Float16)w0.y; t[2]=(_Float16)w0.z; t[3]=(_Float16)w0.w;
                t[4]=(_Float16)w1.x; t[5]=(_Float16)w1.y; t[6]=(_Float16)w1.z; t[7]=(_Float16)w1.w;
                bf[nt] = t;
            }
            #pragma unroll
            for (int mt = 0; mt < 4; ++mt) {
                f16x8 af = *(const f16x8*)&xh[mt*16 + lo][kk*32 + hi*8];
                acc[mt][0] = __builtin_amdgcn_mfma_f32_16x16x32_f16(af, bf[0], acc[mt][0], 0, 0, 0);
                acc[mt][1] = __builtin_amdgcn_mfma_f32_16x16x32_f16(af, bf[1], acc[mt][1], 0, 0, 0);
            }
        }
        const float b0 = bfe[n0 + lo];
        const float b1 = bfe[n0 + 16 + lo];
        #pragma unroll
        for (int mt = 0; mt < 4; ++mt)
            #pragma unroll
            for (int j = 0; j < 4; ++j) {
                fb[mt*16 + hi*4 + j][n0 + lo]      = acc[mt][0][j] + b0;
                fb[mt*16 + hi*4 + j][n0 + 16 + lo] = acc[mt][1][j] + b1;
            }
    }
    __syncthreads();

    {
        const int r = tid >> 2;
        const int q = tid & 3;
        const float4* pf = (const float4*)&fb[r][q << 5];
        float4 v[8];
        float s = 0.f, ss = 0.f;
        #pragma unroll
        for (int i = 0; i < 8; ++i) {
            float4 t = pf[i]; v[i] = t;
            s  += (t.x + t.y) + (t.z + t.w);
            ss += (t.x*t.x + t.y*t.y) + (t.z*t.z + t.w*t.w);
        }
        s  += __shfl_xor(s, 1);  s  += __shfl_xor(s, 2);
        ss += __shfl_xor(ss, 1); ss += __shfl_xor(ss, 2);
        const float mu   = s * (1.f / 128.f);
        const float rstd = rsqrtf(ss * (1.f / 128.f) - mu * mu + 1e-5f);
        const float4* pg = (const float4*)(gf  + (q << 5));
        const float4* pb = (const float4*)(btf + (q << 5));
        #pragma unroll
        for (int i = 0; i < 8; ++i) {
            float4 g = pg[i], bb = pb[i], t = v[i];
            h2t pA, pB;
            pA.x = (_Float16)fmaxf((t.x - mu) * rstd * g.x + bb.x, 0.f);
            pA.y = (_Float16)fmaxf((t.y - mu) * rstd * g.y + bb.y, 0.f);
            pB.x = (_Float16)fmaxf((t.z - mu) * rstd * g.z + bb.z, 0.f);
            pB.y = (_Float16)fmaxf((t.w - mu) * rstd * g.w + bb.w, 0.f);
            uint2 u;
            u.x = __builtin_bit_cast(unsigned int, pA);
            u.y = __builtin_bit_cast(unsigned int, pB);
            *(uint2*)&zh[r][(q << 5) + i * 4] = u;
        }
    }
    __syncthreads();

    {
        const int n0 = wv * 96;
        f16x8 bz[4][4];
        #pragma unroll
        for (int mt = 0; mt < 4; ++mt)
            #pragma unroll
            for (int ks = 0; ks < 4; ++ks)
                bz[mt][ks] = *(const f16x8*)&zh[mt*16 + lo][ks*32 + hi*8];
        #pragma unroll
        for (int nt = 0; nt < 6; ++nt) {
            const int nb = n0 + nt * 16;
            const float4 b4 = *(const float4*)(bih + nb + (hi << 2));
            const float* wr = Wih + (size_t)(nb + lo) * HH;
            f32x4 acc[4];
            #pragma unroll
            for (int mt = 0; mt < 4; ++mt) {
                acc[mt][0]=0.f; acc[mt][1]=0.f; acc[mt][2]=0.f; acc[mt][3]=0.f;
            }
            #pragma unroll
            for (int ks = 0; ks < 4; ++ks) {
                const float4* wp = (const float4*)(wr + ks*32 + hi*8);
                float4 w0 = wp[0], w1 = wp[1];
                f16x8 af;
                af[0]=(_Float16)w0.x; af[1]=(_Float16)w0.y; af[2]=(_Float16)w0.z; af[3]=(_Float16)w0.w;
                af[4]=(_Float16)w1.x; af[5]=(_Float16)w1.y; af[6]=(_Float16)w1.z; af[7]=(_Float16)w1.w;
                #pragma unroll
                for (int mt = 0; mt < 4; ++mt)
                    acc[mt] = __builtin_amdgcn_mfma_f32_16x16x32_f16(af, bz[mt][ks], acc[mt], 0, 0, 0);
            }
            #pragma unroll
            for (int mt = 0; mt < 4; ++mt) {
                h2t pA, pB;
                pA.x = (_Float16)(acc[mt][0] + b4.x);
                pA.y = (_Float16)(acc[mt][1] + b4.y);
                pB.x = (_Float16)(acc[mt][2] + b4.z);
                pB.y = (_Float16)(acc[mt][3] + b4.w);
                uint2 u;
                u.x = __builtin_bit_cast(unsigned int, pA);
                u.y = __builtin_bit_cast(unsigned int, pB);
                *(uint2*)(gxws + (m0 + (size_t)(mt*16 + lo)) * 384 + nb + (hi << 2)) = u;
            }
        }
    }
}

// ======================= PHASE 2 (MFMA recurrence, lean loop) =======================
// 256 blocks x 512 threads; 8 waves do MFMA + gates + cooperative staging.
__global__ void __launch_bounds__(512, 2) p2_kernel(
    const float* __restrict__ hx,  const int* __restrict__ done,
    const float* __restrict__ Whh, const float* __restrict__ bhh,
    unsigned short* __restrict__ gxws, float* __restrict__ out)
{
    const int tid = threadIdx.x;
    const int blk = blockIdx.x;

    __shared__ __align__(16) _Float16 hsh16[2][2][160];      // [buf][chain][pad160]
    __shared__ __align__(16) _Float16 gxb[2][2][CK][384];    // [chain][buf][t][3H] 48 KB
    __shared__ float dshf[2][TT];                            // mask as float

    const int lo = tid & 15;
    const int hi = (tid & 63) >> 4;
    const int wv = tid >> 6;          // 0..7
    const int Y  = lo & 1;            // chain owned by this mfma lane
    const int d0 = wv * 16 + hi * 4;

    // ---- persistent state: Whh A-frags + bias + hprev ----
    f16x8 aW[3][4];
    f32x4 bias[3];
    float hp[4];
    {
        #pragma unroll
        for (int q = 0; q < 3; ++q) {
            const float* wr = Whh + (size_t)(q * 128 + wv * 16 + lo) * HH;
            #pragma unroll
            for (int ks = 0; ks < 4; ++ks) {
                const float4* wp = (const float4*)(wr + ks * 32 + hi * 8);
                float4 w0 = wp[0], w1 = wp[1];
                f16x8 t;
                t[0]=(_Float16)w0.x; t[1]=(_Float16)w0.y; t[2]=(_Float16)w0.z; t[3]=(_Float16)w0.w;
                t[4]=(_Float16)w1.x; t[5]=(_Float16)w1.y; t[6]=(_Float16)w1.z; t[7]=(_Float16)w1.w;
                aW[q][ks] = t;
            }
            bias[q] = *(const f32x4*)&bhh[q * 128 + wv * 16 + hi * 4];
        }
        const float4 h4 = *(const float4*)&hx[(size_t)(2 * blk + Y) * HH + d0];
        hp[0]=h4.x; hp[1]=h4.y; hp[2]=h4.z; hp[3]=h4.w;
    }

    if (tid < 256) {
        const int Yc = tid >> 7, d = tid & 127;
        hsh16[0][Yc][d] = (_Float16)hx[(size_t)(2 * blk + Yc) * HH + d];
    }
    for (int idx = tid; idx < 2 * TT; idx += 512)
        dshf[idx >> 9][idx & 511] =
            done[(2 * blk + (idx >> 9)) * TT + (idx & 511)] ? 0.f : 1.f;

    // ---- cooperative gx staging: 3 ushort4 (8B) per chain per chunk per thread ----
    const unsigned short* baseA = gxws + (size_t)(2 * blk + 0) * TT * 384;
    const unsigned short* baseB = gxws + (size_t)(2 * blk + 1) * TT * 384;
    ushort4 rA0, rA1, rA2, rB0, rB1, rB2;
    {   // chunk 0 -> buffer 0
        const ushort4* ca = (const ushort4*)baseA;
        const ushort4* cb = (const ushort4*)baseB;
        rA0=ca[tid]; rA1=ca[512+tid]; rA2=ca[1024+tid];
        rB0=cb[tid]; rB1=cb[512+tid]; rB2=cb[1024+tid];
        ushort4* ga = (ushort4*)&gxb[0][0][0][0];
        ushort4* gb = (ushort4*)&gxb[1][0][0][0];
        ga[tid]=rA0; ga[512+tid]=rA1; ga[1024+tid]=rA2;
        gb[tid]=rB0; gb[512+tid]=rB1; gb[1024+tid]=rB2;
    }
    __syncthreads();

    // ---- static per-lane pointers (parity-resolved by 2x unroll) ----
    const _Float16* hbE = &hsh16[0][Y][0];       // even t reads buf0
    const _Float16* hbO = &hsh16[1][Y][0];       // odd  t reads buf1
    _Float16* hwE = &hsh16[1][Y][d0];            // even t writes buf1
    _Float16* hwO = &hsh16[0][Y][d0];            // odd  t writes buf0
    float* hraw = (float*)(gxws + (size_t)(2 * blk + Y) * TT * 384) + d0;
    const float* mk = &dshf[Y][0];
    const _Float16* gx0 = &gxb[Y][0][0][d0];     // chunk-even gx base
    const _Float16* gx1 = &gxb[Y][1][0][d0];     // chunk-odd  gx base

    #define GSTEP(HB, HW, MASKT) { \
        f16x8 B0 = *(const f16x8*)&(HB)[0   + hi*8]; \
        f16x8 B1 = *(const f16x8*)&(HB)[32  + hi*8]; \
        f16x8 B2 = *(const f16x8*)&(HB)[64  + hi*8]; \
        f16x8 B3 = *(const f16x8*)&(HB)[96  + hi*8]; \
        f16x4 g0 = *(const f16x4*)&gx[0]; \
        f16x4 g1 = *(const f16x4*)&gx[128]; \
        f16x4 g2 = *(const f16x4*)&gx[256]; \
        const float mask = (MASKT); \
        f32x4 a0 = bias[0], a1 = bias[1], a2 = bias[2]; \
        a0 = __builtin_amdgcn_mfma_f32_16x16x32_f16(aW[0][0], B0, a0, 0, 0, 0); \
        a1 = __builtin_amdgcn_mfma_f32_16x16x32_f16(aW[1][0], B0, a1, 0, 0, 0); \
        a2 = __builtin_amdgcn_mfma_f32_16x16x32_f16(aW[2][0], B0, a2, 0, 0, 0); \
        a0 = __builtin_amdgcn_mfma_f32_16x16x32_f16(aW[0][1], B1, a0, 0, 0, 0); \
        a1 = __builtin_amdgcn_mfma_f32_16x16x32_f16(aW[1][1], B1, a1, 0, 0, 0); \
        a2 = __builtin_amdgcn_mfma_f32_16x16x32_f16(aW[2][1], B1, a2, 0, 0, 0); \
        a0 = __builtin_amdgcn_mfma_f32_16x16x32_f16(aW[0][2], B2, a0, 0, 0, 0); \
        a1 = __builtin_amdgcn_mfma_f32_16x16x32_f16(aW[1][2], B2, a1, 0, 0, 0); \
        a2 = __builtin_amdgcn_mfma_f32_16x16x32_f16(aW[2][2], B2, a2, 0, 0, 0); \
        a0 = __builtin_amdgcn_mfma_f32_16x16x32_f16(aW[0][3], B3, a0, 0, 0, 0); \
        a1 = __builtin_amdgcn_mfma_f32_16x16x32_f16(aW[1][3], B3, a1, 0, 0, 0); \
        a2 = __builtin_amdgcn_mfma_f32_16x16x32_f16(aW[2][3], B3, a2, 0, 0, 0); \
        float hn[4]; \
        _Pragma("unroll") \
        for (int jj = 0; jj < 4; ++jj) { \
            float xr = (float)g0[jj] + a0[jj]; \
            float xz = (float)g1[jj] + a1[jj]; \
            float r_ = __builtin_amdgcn_rcpf(1.f + __builtin_amdgcn_exp2f(xr * -1.44269504f)); \
            float u_ = __builtin_amdgcn_rcpf(1.f + __builtin_amdgcn_exp2f(xz * -1.44269504f)); \
            float a_ = (float)g2[jj] + r_ * a2[jj]; \
            a_ = fminf(fmaxf(a_, -20.f), 20.f); \
            float e2 = __builtin_amdgcn_exp2f(a_ * 2.88539008f); \
            float nn = 1.f - 2.f * __builtin_amdgcn_rcpf(e2 + 1.f); \
            float hnew = nn + u_ * (hp[jj] - nn); \
            hn[jj] = hnew; \
            hp[jj] = hnew * mask; \
        } \
        if (lo < 2) { \
            uint2 u; \
            u.x = __builtin_bit_cast(unsigned int, __builtin_amdgcn_cvt_pkrtz(hp[0], hp[1])); \
            u.y = __builtin_bit_cast(unsigned int, __builtin_amdgcn_cvt_pkrtz(hp[2], hp[3])); \
            *(uint2*)(HW) = u; \
            *(float4*)hraw = make_float4(hn[0], hn[1], hn[2], hn[3]); \
        } \
        gx += 384; hraw += 192; \
    }

    for (int c = 0; c < NCK; ++c) {
        if (c + 1 < NCK) {   // issue next-chunk loads (16-step slack)
            const ushort4* ca = (const ushort4*)(baseA + (size_t)(c + 1) * CK * 384);
            const ushort4* cb = (const ushort4*)(baseB + (size_t)(c + 1) * CK * 384);
            rA0=ca[tid]; rA1=ca[512+tid]; rA2=ca[1024+tid];
            rB0=cb[tid]; rB1=cb[512+tid]; rB2=cb[1024+tid];
        }
        const _Float16* gx = (c & 1) ? gx1 : gx0;
        const float* mkc = mk + c * CK;
        #pragma unroll
        for (int jp = 0; jp < CK; jp += 2) {
            GSTEP(hbE, hwE, mkc[jp])          // even step: read buf0, write buf1
            BAR();
            GSTEP(hbO, hwO, mkc[jp + 1])      // odd step: read buf1, write buf0
            if (jp == CK - 2 && c + 1 < NCK) {  // staged regs -> opposite gx buffer
                const int nb = (c + 1) & 1;
                ushort4* ga = (ushort4*)&gxb[0][nb][0][0];
                ushort4* gb = (ushort4*)&gxb[1][nb][0][0];
                ga[tid]=rA0; ga[512+tid]=rA1; ga[1024+tid]=rA2;
                gb[tid]=rB0; gb[512+tid]=rB1; gb[1024+tid]=rB2;
            }
            BAR();
        }
    }

    // epilogue: final masked h (hp) -> out
    if (lo < 2)
        *(float4*)&out[HFIN + (size_t)(2 * blk + Y) * HH + d0] =
            make_float4(hp[0], hp[1], hp[2], hp[3]);
}

// ======================= PHASE 3 (LN + heads, wide — unchanged from R14) =======================
__global__ void __launch_bounds__(256, 2) p3_kernel(
    const unsigned short* __restrict__ gxws,
    const float* __restrict__ gr,  const float* __restrict__ btr,
    const float* __restrict__ Wp,  const float* __restrict__ bp,
    const float* __restrict__ Wv,  const float* __restrict__ bv,
    float* __restrict__ out)
{
    const int tid = threadIdx.x;
    __shared__ __align__(16) float wpl[9][132];
    __shared__ float bpl[9];

    for (int idx = tid; idx < 9 * HH; idx += 256) {
        int row = idx >> 7, col = idx & 127;
        wpl[row][col] = (row < 8) ? Wp[row * HH + col] : Wv[col];
    }
    if (tid < 9) bpl[tid] = (tid < 8) ? bp[tid] : bv[0];

    const size_t m = (size_t)blockIdx.x * 64 + (tid >> 2);
    const int q = tid & 3;
    const float* hr = (const float*)(gxws + m * 384);

    float4 v[8];
    float s = 0.f, ss = 0.f;
    #pragma unroll
    for (int j = 0; j < 8; ++j) {
        float4 t = ((const float4*)hr)[q + 4 * j];
        v[j] = t;
        s  += (t.x + t.y) + (t.z + t.w);
        ss += (t.x*t.x + t.y*t.y) + (t.z*t.z + t.w*t.w);
    }
    s  += __shfl_xor(s, 1);  s  += __shfl_xor(s, 2);
    ss += __shfl_xor(ss, 1); ss += __shfl_xor(ss, 2);
    const float mu   = s * (1.f / 128.f);
    const float rstd = rsqrtf(ss * (1.f / 128.f) - mu * mu + 1e-5f);

    float4 y[8];
    #pragma unroll
    for (int j = 0; j < 8; ++j) {
        float4 g  = ((const float4*)gr)[q + 4 * j];
        float4 bb = ((const float4*)btr)[q + 4 * j];
        float4 t = v[j];
        y[j].x = (t.x - mu) * rstd * g.x + bb.x;
        y[j].y = (t.y - mu) * rstd * g.y + bb.y;
        y[j].z = (t.z - mu) * rstd * g.z + bb.z;
        y[j].w = (t.w - mu) * rstd * g.w + bb.w;
    }
    __syncthreads();   // wpl staged

    float acc[9];
    #pragma unroll
    for (int hd = 0; hd < 9; ++hd) {
        float a = 0.f;
        #pragma unroll
        for (int j = 0; j < 8; ++j) {
            float4 w = ((const float4*)wpl[hd])[q + 4 * j];
            a += (y[j].x * w.x + y[j].y * w.y) + (y[j].z * w.z + y[j].w * w.w);
        }
        acc[hd] = a;
    }
    #pragma unroll
    for (int hd = 0; hd < 9; ++hd) {
        acc[hd] += __shfl_xor(acc[hd], 1);
        acc[hd] += __shfl_xor(acc[hd], 2);
    }
    if (q == 0) {
        float4 o0 = make_float4(acc[0] + bpl[0], acc[1] + bpl[1], acc[2] + bpl[2], acc[3] + bpl[3]);
        float4 o1 = make_float4(acc[4] + bpl[4], acc[5] + bpl[5], acc[6] + bpl[6], acc[7] + bpl[7]);
        ((float4*)(out + m * AA))[0] = o0;
        ((float4*)(out + m * AA))[1] = o1;
    } else if (q == 1) {
        out[VALO + m] = acc[8] + bpl[8];
    }
}

extern "C" void kernel_launch(void* const* d_in, const int* in_sizes, int n_in,
                              void* d_out, int out_size, void* d_ws, size_t ws_size,
                              hipStream_t stream) {
    const float* x   = (const float*)d_in[0];
    const float* hx  = (const float*)d_in[1];
    const int*   dn  = (const int*)d_in[2];
    const float* Wf  = (const float*)d_in[3];
    const float* bfe = (const float*)d_in[4];
    const float* gf  = (const float*)d_in[5];
    const float* btf = (const float*)d_in[6];
    const float* Wih = (const float*)d_in[7];
    const float* Whh = (const float*)d_in[8];
    const float* bih = (const float*)d_in[9];
    const float* bhh = (const float*)d_in[10];
    const float* gr  = (const float*)d_in[11];
    const float* btr = (const float*)d_in[12];
    const float* Wp  = (const float*)d_in[13];
    const float* bp  = (const float*)d_in[14];
    const float* Wv  = (const float*)d_in[15];
    const float* bv  = (const float*)d_in[16];
    float* out = (float*)d_out;

    unsigned short* gxws = (unsigned short*)d_ws;   // 201.3 MB gx buffer (+hraw reuse)
    hipLaunchKernelGGL(p1_kernel, dim3(BB * TT / 64), dim3(256), 0, stream,
                       x, Wf, bfe, gf, btf, Wih, bih, gxws);
    hipLaunchKernelGGL(p2_kernel, dim3(BB / 2), dim3(512), 0, stream,
                       hx, dn, Whh, bhh, gxws, out);
    hipLaunchKernelGGL(p3_kernel, dim3(BB * TT / 64), dim3(256), 0, stream,
                       gxws, gr, btr, Wp, bp, Wv, bv, out);
}

// Round 8
// 506.639 us; speedup vs baseline: 1.3518x; 1.2567x over previous
//
#include <hip/hip_runtime.h>

// RecurrentActorCritic B=512,T=512,S=64,H=128,A=8 (fp32 I/O).
// R18: spread gates across redundant B-columns. R17 post-mortem: step
// 1807cyc, VALU 1043/SIMD dominated by gates = 92 VALU + 24 TRANS ops
// (quarter-rate, ~192cyc/wave) computing 4 GRU units/lane with results
// 8x-redundant (cols 0-15 all hold the chain pair since Y=lo&1). Now:
// lane (hi,lo) q=(lo>>1)&3 processes ONE unit (row hi*4+q, chain lo&1);
// a*[q] selected by 3 hoisted-mask ternaries (no runtime reg index);
// lo<8 lanes write (32 units/wave covered); gx read = 3x ds_read_u16;
// h write = ds_write_b16; clamp dropped (1-2*rcp(F+1) saturates, no NaN).
// Gates: 92+24t -> ~26+6t per wave. p1 = R11, p3 = R14 (unchanged).

typedef _Float16 h2t __attribute__((ext_vector_type(2)));
typedef _Float16 f16x4 __attribute__((ext_vector_type(4)));
typedef _Float16 f16x8 __attribute__((ext_vector_type(8)));
typedef float f32x4 __attribute__((ext_vector_type(4)));

// LDS-only barrier: drain ds ops, leave global loads/stores in flight.
#define BAR() __asm__ volatile("s_waitcnt lgkmcnt(0)\n\ts_barrier" ::: "memory")

#define BB 512
#define TT 512
#define SS 64
#define HH 128
#define AA 8
#define CK 16
#define NCK (TT / CK)
#define VALO (BB * TT * AA)
#define HFIN (VALO + BB * TT)

// ======================= PHASE 1 (MFMA, unchanged from R11) =======================
__global__ void __launch_bounds__(256, 2) p1_kernel(
    const float* __restrict__ x,   const float* __restrict__ Wf,
    const float* __restrict__ bfe, const float* __restrict__ gf,
    const float* __restrict__ btf, const float* __restrict__ Wih,
    const float* __restrict__ bih, unsigned short* __restrict__ gxws)
{
    const int tid = threadIdx.x;
    const int wv  = tid >> 6;
    const int l   = tid & 63;
    const int lo  = l & 15;
    const int hi  = l >> 4;
    const size_t m0 = (size_t)blockIdx.x * 64;

    __shared__ __align__(16) _Float16 xh[64][72];
    __shared__ __align__(16) float    fb[64][132];
    __shared__ __align__(16) _Float16 zh[64][136];

    {
        const int r  = tid >> 2;
        const int c0 = (tid & 3) << 4;
        const float4* px = (const float4*)(x + (m0 + (size_t)r) * SS + c0);
        float4 a = px[0], b = px[1], c = px[2], d = px[3];
        f16x8 h0, h1;
        h0[0]=(_Float16)a.x; h0[1]=(_Float16)a.y; h0[2]=(_Float16)a.z; h0[3]=(_Float16)a.w;
        h0[4]=(_Float16)b.x; h0[5]=(_Float16)b.y; h0[6]=(_Float16)b.z; h0[7]=(_Float16)b.w;
        h1[0]=(_Float16)c.x; h1[1]=(_Float16)c.y; h1[2]=(_Float16)c.z; h1[3]=(_Float16)c.w;
        h1[4]=(_Float16)d.x; h1[5]=(_Float16)d.y; h1[6]=(_Float16)d.z; h1[7]=(_Float16)d.w;
        *(f16x8*)&xh[r][c0]     = h0;
        *(f16x8*)&xh[r][c0 + 8] = h1;
    }
    __syncthreads();

    {
        const int n0 = wv << 5;
        f32x4 acc[4][2];
        #pragma unroll
        for (int mt = 0; mt < 4; ++mt)
            #pragma unroll
            for (int nt = 0; nt < 2; ++nt) {
                acc[mt][nt][0]=0.f; acc[mt][nt][1]=0.f;
                acc[mt][nt][2]=0.f; acc[mt][nt][3]=0.f;
            }
        #pragma unroll
        for (int kk = 0; kk < 2; ++kk) {
            f16x8 bf[2];
            #pragma unroll
            for (int nt = 0; nt < 2; ++nt) {
                const float4* wp = (const float4*)(Wf + (size_t)(n0 + nt*16 + lo) * SS + kk*32 + hi*8);
                float4 w0 = wp[0], w1 = wp[1];
                f16x8 t;
                t[0]=(_Float16)w0.x; t[1]=(_Float16)w0.y; t[2]=(_Float16)w0.z; t[3]=(_Float16)w0.w;
                t[4]=(_Float16)w1.x; t[5]=(_Float16)w1.y; t[6]=(_Float16)w1.z; t[7]=(_Float16)w1.w;
                bf[nt] = t;
            }
            #pragma unroll
            for (int mt = 0; mt < 4; ++mt) {
                f16x8 af = *(const f16x8*)&xh[mt*16 + lo][kk*32 + hi*8];
                acc[mt][0] = __builtin_amdgcn_mfma_f32_16x16x32_f16(af, bf[0], acc[mt][0], 0, 0, 0);
                acc[mt][1] = __builtin_amdgcn_mfma_f32_16x16x32_f16(af, bf[1], acc[mt][1], 0, 0, 0);
            }
        }
        const float b0 = bfe[n0 + lo];
        const float b1 = bfe[n0 + 16 + lo];
        #pragma unroll
        for (int mt = 0; mt < 4; ++mt)
            #pragma unroll
            for (int j = 0; j < 4; ++j) {
                fb[mt*16 + hi*4 + j][n0 + lo]      = acc[mt][0][j] + b0;
                fb[mt*16 + hi*4 + j][n0 + 16 + lo] = acc[mt][1][j] + b1;
            }
    }
    __syncthreads();

    {
        const int r = tid >> 2;
        const int q = tid & 3;
        const float4* pf = (const float4*)&fb[r][q << 5];
        float4 v[8];
        float s = 0.f, ss = 0.f;
        #pragma unroll
        for (int i = 0; i < 8; ++i) {
            float4 t = pf[i]; v[i] = t;
            s  += (t.x + t.y) + (t.z + t.w);
            ss += (t.x*t.x + t.y*t.y) + (t.z*t.z + t.w*t.w);
        }
        s  += __shfl_xor(s, 1);  s  += __shfl_xor(s, 2);
        ss += __shfl_xor(ss, 1); ss += __shfl_xor(ss, 2);
        const float mu   = s * (1.f / 128.f);
        const float rstd = rsqrtf(ss * (1.f / 128.f) - mu * mu + 1e-5f);
        const float4* pg = (const float4*)(gf  + (q << 5));
        const float4* pb = (const float4*)(btf + (q << 5));
        #pragma unroll
        for (int i = 0; i < 8; ++i) {
            float4 g = pg[i], bb = pb[i], t = v[i];
            h2t pA, pB;
            pA.x = (_Float16)fmaxf((t.x - mu) * rstd * g.x + bb.x, 0.f);
            pA.y = (_Float16)fmaxf((t.y - mu) * rstd * g.y + bb.y, 0.f);
            pB.x = (_Float16)fmaxf((t.z - mu) * rstd * g.z + bb.z, 0.f);
            pB.y = (_Float16)fmaxf((t.w - mu) * rstd * g.w + bb.w, 0.f);
            uint2 u;
            u.x = __builtin_bit_cast(unsigned int, pA);
            u.y = __builtin_bit_cast(unsigned int, pB);
            *(uint2*)&zh[r][(q << 5) + i * 4] = u;
        }
    }
    __syncthreads();

    {
        const int n0 = wv * 96;
        f16x8 bz[4][4];
        #pragma unroll
        for (int mt = 0; mt < 4; ++mt)
            #pragma unroll
            for (int ks = 0; ks < 4; ++ks)
                bz[mt][ks] = *(const f16x8*)&zh[mt*16 + lo][ks*32 + hi*8];
        #pragma unroll
        for (int nt = 0; nt < 6; ++nt) {
            const int nb = n0 + nt * 16;
            const float4 b4 = *(const float4*)(bih + nb + (hi << 2));
            const float* wr = Wih + (size_t)(nb + lo) * HH;
            f32x4 acc[4];
            #pragma unroll
            for (int mt = 0; mt < 4; ++mt) {
                acc[mt][0]=0.f; acc[mt][1]=0.f; acc[mt][2]=0.f; acc[mt][3]=0.f;
            }
            #pragma unroll
            for (int ks = 0; ks < 4; ++ks) {
                const float4* wp = (const float4*)(wr + ks*32 + hi*8);
                float4 w0 = wp[0], w1 = wp[1];
                f16x8 af;
                af[0]=(_Float16)w0.x; af[1]=(_Float16)w0.y; af[2]=(_Float16)w0.z; af[3]=(_Float16)w0.w;
                af[4]=(_Float16)w1.x; af[5]=(_Float16)w1.y; af[6]=(_Float16)w1.z; af[7]=(_Float16)w1.w;
                #pragma unroll
                for (int mt = 0; mt < 4; ++mt)
                    acc[mt] = __builtin_amdgcn_mfma_f32_16x16x32_f16(af, bz[mt][ks], acc[mt], 0, 0, 0);
            }
            #pragma unroll
            for (int mt = 0; mt < 4; ++mt) {
                h2t pA, pB;
                pA.x = (_Float16)(acc[mt][0] + b4.x);
                pA.y = (_Float16)(acc[mt][1] + b4.y);
                pB.x = (_Float16)(acc[mt][2] + b4.z);
                pB.y = (_Float16)(acc[mt][3] + b4.w);
                uint2 u;
                u.x = __builtin_bit_cast(unsigned int, pA);
                u.y = __builtin_bit_cast(unsigned int, pB);
                *(uint2*)(gxws + (m0 + (size_t)(mt*16 + lo)) * 384 + nb + (hi << 2)) = u;
            }
        }
    }
}

// ======================= PHASE 2 (MFMA recurrence, spread gates) =======================
// 256 blocks x 512 threads; 8 waves do MFMA + 1-unit-per-lane gates + staging.
__global__ void __launch_bounds__(512, 2) p2_kernel(
    const float* __restrict__ hx,  const int* __restrict__ done,
    const float* __restrict__ Whh, const float* __restrict__ bhh,
    unsigned short* __restrict__ gxws, float* __restrict__ out)
{
    const int tid = threadIdx.x;
    const int blk = blockIdx.x;

    __shared__ __align__(16) _Float16 hsh16[2][2][160];      // [buf][chain][pad160]
    __shared__ __align__(16) _Float16 gxb[2][2][CK][384];    // [chain][buf][t][3H] 48 KB
    __shared__ float dshf[2][TT];                            // mask as float

    const int lo = tid & 15;
    const int hi = (tid & 63) >> 4;
    const int wv = tid >> 6;          // 0..7
    const int Y  = lo & 1;            // chain in this lane's B-column
    const int q  = (lo >> 1) & 3;     // which acc reg this lane's unit uses
    const int du = wv * 16 + hi * 4 + q;   // GRU unit dim (0..127)
    const bool wr = (lo < 8);         // unique (q,Y) writers
    const bool qb0 = ((lo >> 1) & 1) != 0;
    const bool qb1 = ((lo >> 2) & 1) != 0;

    // ---- persistent state: Whh A-frags + bias + hprev (1 unit/lane) ----
    f16x8 aW[3][4];
    f32x4 bias[3];
    float hp;
    {
        #pragma unroll
        for (int g = 0; g < 3; ++g) {
            const float* wrp = Whh + (size_t)(g * 128 + wv * 16 + lo) * HH;
            #pragma unroll
            for (int ks = 0; ks < 4; ++ks) {
                const float4* wp = (const float4*)(wrp + ks * 32 + hi * 8);
                float4 w0 = wp[0], w1 = wp[1];
                f16x8 t;
                t[0]=(_Float16)w0.x; t[1]=(_Float16)w0.y; t[2]=(_Float16)w0.z; t[3]=(_Float16)w0.w;
                t[4]=(_Float16)w1.x; t[5]=(_Float16)w1.y; t[6]=(_Float16)w1.z; t[7]=(_Float16)w1.w;
                aW[g][ks] = t;
            }
            bias[g] = *(const f32x4*)&bhh[g * 128 + wv * 16 + hi * 4];
        }
        hp = hx[(size_t)(2 * blk + Y) * HH + du];
    }

    if (tid < 256) {
        const int Yc = tid >> 7, d = tid & 127;
        hsh16[0][Yc][d] = (_Float16)hx[(size_t)(2 * blk + Yc) * HH + d];
    }
    for (int idx = tid; idx < 2 * TT; idx += 512)
        dshf[idx >> 9][idx & 511] =
            done[(2 * blk + (idx >> 9)) * TT + (idx & 511)] ? 0.f : 1.f;

    // ---- cooperative gx staging: 3 ushort4 (8B) per chain per chunk per thread ----
    const unsigned short* baseA = gxws + (size_t)(2 * blk + 0) * TT * 384;
    const unsigned short* baseB = gxws + (size_t)(2 * blk + 1) * TT * 384;
    ushort4 rA0, rA1, rA2, rB0, rB1, rB2;
    {   // chunk 0 -> buffer 0
        const ushort4* ca = (const ushort4*)baseA;
        const ushort4* cb = (const ushort4*)baseB;
        rA0=ca[tid]; rA1=ca[512+tid]; rA2=ca[1024+tid];
        rB0=cb[tid]; rB1=cb[512+tid]; rB2=cb[1024+tid];
        ushort4* ga = (ushort4*)&gxb[0][0][0][0];
        ushort4* gb = (ushort4*)&gxb[1][0][0][0];
        ga[tid]=rA0; ga[512+tid]=rA1; ga[1024+tid]=rA2;
        gb[tid]=rB0; gb[512+tid]=rB1; gb[1024+tid]=rB2;
    }
    __syncthreads();

    // ---- static per-lane pointers (parity-resolved by 2x unroll) ----
    const _Float16* hbE = &hsh16[0][Y][0];       // even t reads buf0
    const _Float16* hbO = &hsh16[1][Y][0];       // odd  t reads buf1
    _Float16* hwE = &hsh16[1][Y][du];            // even t writes buf1
    _Float16* hwO = &hsh16[0][Y][du];            // odd  t writes buf0
    float* hraw = (float*)(gxws + (size_t)(2 * blk + Y) * TT * 384) + du;
    const float* mk = &dshf[Y][0];
    const _Float16* gx0 = &gxb[Y][0][0][du];     // chunk-even gx base
    const _Float16* gx1 = &gxb[Y][1][0][du];     // chunk-odd  gx base

    #define GSTEP(HB, HW, MASKT) { \
        f16x8 B0 = *(const f16x8*)&(HB)[0   + hi*8]; \
        f16x8 B1 = *(const f16x8*)&(HB)[32  + hi*8]; \
        f16x8 B2 = *(const f16x8*)&(HB)[64  + hi*8]; \
        f16x8 B3 = *(const f16x8*)&(HB)[96  + hi*8]; \
        const float gr0 = (float)gx[0]; \
        const float gz0 = (float)gx[128]; \
        const float gn0 = (float)gx[256]; \
        const float mask = (MASKT); \
        f32x4 a0 = bias[0], a1 = bias[1], a2 = bias[2]; \
        a0 = __builtin_amdgcn_mfma_f32_16x16x32_f16(aW[0][0], B0, a0, 0, 0, 0); \
        a1 = __builtin_amdgcn_mfma_f32_16x16x32_f16(aW[1][0], B0, a1, 0, 0, 0); \
        a2 = __builtin_amdgcn_mfma_f32_16x16x32_f16(aW[2][0], B0, a2, 0, 0, 0); \
        a0 = __builtin_amdgcn_mfma_f32_16x16x32_f16(aW[0][1], B1, a0, 0, 0, 0); \
        a1 = __builtin_amdgcn_mfma_f32_16x16x32_f16(aW[1][1], B1, a1, 0, 0, 0); \
        a2 = __builtin_amdgcn_mfma_f32_16x16x32_f16(aW[2][1], B1, a2, 0, 0, 0); \
        a0 = __builtin_amdgcn_mfma_f32_16x16x32_f16(aW[0][2], B2, a0, 0, 0, 0); \
        a1 = __builtin_amdgcn_mfma_f32_16x16x32_f16(aW[1][2], B2, a1, 0, 0, 0); \
        a2 = __builtin_amdgcn_mfma_f32_16x16x32_f16(aW[2][2], B2, a2, 0, 0, 0); \
        a0 = __builtin_amdgcn_mfma_f32_16x16x32_f16(aW[0][3], B3, a0, 0, 0, 0); \
        a1 = __builtin_amdgcn_mfma_f32_16x16x32_f16(aW[1][3], B3, a1, 0, 0, 0); \
        a2 = __builtin_amdgcn_mfma_f32_16x16x32_f16(aW[2][3], B3, a2, 0, 0, 0); \
        float xr_a = qb1 ? (qb0 ? a0[3] : a0[2]) : (qb0 ? a0[1] : a0[0]); \
        float xz_a = qb1 ? (qb0 ? a1[3] : a1[2]) : (qb0 ? a1[1] : a1[0]); \
        float hn_a = qb1 ? (qb0 ? a2[3] : a2[2]) : (qb0 ? a2[1] : a2[0]); \
        float xr = gr0 + xr_a; \
        float xz = gz0 + xz_a; \
        float r_ = __builtin_amdgcn_rcpf(1.f + __builtin_amdgcn_exp2f(xr * -1.44269504f)); \
        float u_ = __builtin_amdgcn_rcpf(1.f + __builtin_amdgcn_exp2f(xz * -1.44269504f)); \
        float a_ = gn0 + r_ * hn_a; \
        float F  = __builtin_amdgcn_exp2f(a_ * 2.88539008f); \
        float nn = 1.f - 2.f * __builtin_amdgcn_rcpf(F + 1.f); \
        float hnew = nn + u_ * (hp - nn); \
        hp = hnew * mask; \
        if (wr) { \
            *(HW) = (_Float16)hp; \
            *hraw = hnew; \
        } \
        gx += 384; hraw += 192; \
    }

    for (int c = 0; c < NCK; ++c) {
        if (c + 1 < NCK) {   // issue next-chunk loads (16-step slack)
            const ushort4* ca = (const ushort4*)(baseA + (size_t)(c + 1) * CK * 384);
            const ushort4* cb = (const ushort4*)(baseB + (size_t)(c + 1) * CK * 384);
            rA0=ca[tid]; rA1=ca[512+tid]; rA2=ca[1024+tid];
            rB0=cb[tid]; rB1=cb[512+tid]; rB2=cb[1024+tid];
        }
        const _Float16* gx = (c & 1) ? gx1 : gx0;
        const float* mkc = mk + c * CK;
        #pragma unroll
        for (int jp = 0; jp < CK; jp += 2) {
            GSTEP(hbE, hwE, mkc[jp])          // even step: read buf0, write buf1
            BAR();
            GSTEP(hbO, hwO, mkc[jp + 1])      // odd step: read buf1, write buf0
            if (jp == CK - 2 && c + 1 < NCK) {  // staged regs -> opposite gx buffer
                const int nb = (c + 1) & 1;
                ushort4* ga = (ushort4*)&gxb[0][nb][0][0];
                ushort4* gb = (ushort4*)&gxb[1][nb][0][0];
                ga[tid]=rA0; ga[512+tid]=rA1; ga[1024+tid]=rA2;
                gb[tid]=rB0; gb[512+tid]=rB1; gb[1024+tid]=rB2;
            }
            BAR();
        }
    }

    // epilogue: final masked h (hp) -> out
    if (wr)
        out[HFIN + (size_t)(2 * blk + Y) * HH + du] = hp;
}

// ======================= PHASE 3 (LN + heads, wide — unchanged from R14) =======================
__global__ void __launch_bounds__(256, 2) p3_kernel(
    const unsigned short* __restrict__ gxws,
    const float* __restrict__ gr,  const float* __restrict__ btr,
    const float* __restrict__ Wp,  const float* __restrict__ bp,
    const float* __restrict__ Wv,  const float* __restrict__ bv,
    float* __restrict__ out)
{
    const int tid = threadIdx.x;
    __shared__ __align__(16) float wpl[9][132];
    __shared__ float bpl[9];

    for (int idx = tid; idx < 9 * HH; idx += 256) {
        int row = idx >> 7, col = idx & 127;
        wpl[row][col] = (row < 8) ? Wp[row * HH + col] : Wv[col];
    }
    if (tid < 9) bpl[tid] = (tid < 8) ? bp[tid] : bv[0];

    const size_t m = (size_t)blockIdx.x * 64 + (tid >> 2);
    const int q = tid & 3;
    const float* hr = (const float*)(gxws + m * 384);

    float4 v[8];
    float s = 0.f, ss = 0.f;
    #pragma unroll
    for (int j = 0; j < 8; ++j) {
        float4 t = ((const float4*)hr)[q + 4 * j];
        v[j] = t;
        s  += (t.x + t.y) + (t.z + t.w);
        ss += (t.x*t.x + t.y*t.y) + (t.z*t.z + t.w*t.w);
    }
    s  += __shfl_xor(s, 1);  s  += __shfl_xor(s, 2);
    ss += __shfl_xor(ss, 1); ss += __shfl_xor(ss, 2);
    const float mu   = s * (1.f / 128.f);
    const float rstd = rsqrtf(ss * (1.f / 128.f) - mu * mu + 1e-5f);

    float4 y[8];
    #pragma unroll
    for (int j = 0; j < 8; ++j) {
        float4 g  = ((const float4*)gr)[q + 4 * j];
        float4 bb = ((const float4*)btr)[q + 4 * j];
        float4 t = v[j];
        y[j].x = (t.x - mu) * rstd * g.x + bb.x;
        y[j].y = (t.y - mu) * rstd * g.y + bb.y;
        y[j].z = (t.z - mu) * rstd * g.z + bb.z;
        y[j].w = (t.w - mu) * rstd * g.w + bb.w;
    }
    __syncthreads();   // wpl staged

    float acc[9];
    #pragma unroll
    for (int hd = 0; hd < 9; ++hd) {
        float a = 0.f;
        #pragma unroll
        for (int j = 0; j < 8; ++j) {
            float4 w = ((const float4*)wpl[hd])[q + 4 * j];
            a += (y[j].x * w.x + y[j].y * w.y) + (y[j].z * w.z + y[j].w * w.w);
        }
        acc[hd] = a;
    }
    #pragma unroll
    for (int hd = 0; hd < 9; ++hd) {
        acc[hd] += __shfl_xor(acc[hd], 1);
        acc[hd] += __shfl_xor(acc[hd], 2);
    }
    if (q == 0) {
        float4 o0 = make_float4(acc[0] + bpl[0], acc[1] + bpl[1], acc[2] + bpl[2], acc[3] + bpl[3]);
        float4 o1 = make_float4(acc[4] + bpl[4], acc[5] + bpl[5], acc[6] + bpl[6], acc[7] + bpl[7]);
        ((float4*)(out + m * AA))[0] = o0;
        ((float4*)(out + m * AA))[1] = o1;
    } else if (q == 1) {
        out[VALO + m] = acc[8] + bpl[8];
    }
}

extern "C" void kernel_launch(void* const* d_in, const int* in_sizes, int n_in,
                              void* d_out, int out_size, void* d_ws, size_t ws_size,
                              hipStream_t stream) {
    const float* x   = (const float*)d_in[0];
    const float* hx  = (const float*)d_in[1];
    const int*   dn  = (const int*)d_in[2];
    const float* Wf  = (const float*)d_in[3];
    const float* bfe = (const float*)d_in[4];
    const float* gf  = (const float*)d_in[5];
    const float* btf = (const float*)d_in[6];
    const float* Wih = (const float*)d_in[7];
    const float* Whh = (const float*)d_in[8];
    const float* bih = (const float*)d_in[9];
    const float* bhh = (const float*)d_in[10];
    const float* gr  = (const float*)d_in[11];
    const float* btr = (const float*)d_in[12];
    const float* Wp  = (const float*)d_in[13];
    const float* bp  = (const float*)d_in[14];
    const float* Wv  = (const float*)d_in[15];
    const float* bv  = (const float*)d_in[16];
    float* out = (float*)d_out;

    unsigned short* gxws = (unsigned short*)d_ws;   // 201.3 MB gx buffer (+hraw reuse)
    hipLaunchKernelGGL(p1_kernel, dim3(BB * TT / 64), dim3(256), 0, stream,
                       x, Wf, bfe, gf, btf, Wih, bih, gxws);
    hipLaunchKernelGGL(p2_kernel, dim3(BB / 2), dim3(512), 0, stream,
                       hx, dn, Whh, bhh, gxws, out);
    hipLaunchKernelGGL(p3_kernel, dim3(BB * TT / 64), dim3(256), 0, stream,
                       gxws, gr, btr, Wp, bp, Wv, bv, out);
}